// Round 14
// baseline (198.126 us; speedup 1.0000x reference)
//
#include <hip/hip_runtime.h>
#include <hip/hip_bf16.h>

typedef unsigned short u16;
typedef unsigned int u32;
typedef __attribute__((ext_vector_type(8))) short bf16x8;
typedef __attribute__((ext_vector_type(4))) float f32x4;
typedef __attribute__((ext_vector_type(16))) float f32x16;

#define AS1(p) ((const __attribute__((address_space(1))) void*)(p))
#define AS3(p) ((__attribute__((address_space(3))) void*)(p))
#define STG(src, dst) __builtin_amdgcn_global_load_lds(AS1(src), AS3(dst), 16, 0, 0)

#if __has_builtin(__builtin_amdgcn_exp2f)
#define EXP2F(x) __builtin_amdgcn_exp2f(x)
#else
#define EXP2F(x) exp2f(x)
#endif

static __device__ __forceinline__ float b2f(u16 u) {
  union { unsigned int i; float f; } v; v.i = ((unsigned int)u) << 16; return v.f;
}
static __device__ __forceinline__ u16 f2b(float f) {
  union { float f; unsigned int i; } v; v.f = f;
  unsigned int r = v.i + 0x7FFFu + ((v.i >> 16) & 1u);
  return (u16)(r >> 16);
}
static __device__ __forceinline__ u32 cvt_pk_bf16(float lo, float hi) {
  u32 r;
  asm("v_cvt_pk_bf16_f32 %0, %1, %2" : "=v"(r) : "v"(lo), "v"(hi));
  return r;
}
static __device__ __forceinline__ void permswap(u32& a, u32& b) {
  asm("v_permlane32_swap_b32 %0, %1" : "+v"(a), "+v"(b));
}

// ---------------- fp32 -> bf16 cast (vectorized, grid-stride) ----------------
__global__ __launch_bounds__(256) void cast_f32_bf16(const float* __restrict__ src,
                                                     u16* __restrict__ dst, int n8) {
  int stride = gridDim.x * blockDim.x;
  for (int i = blockIdx.x * blockDim.x + threadIdx.x; i < n8; i += stride) {
    const float4* s = (const float4*)(src + (size_t)i * 8);
    float4 a = s[0], b = s[1];
    bf16x8 o;
    o[0] = (short)f2b(a.x); o[1] = (short)f2b(a.y); o[2] = (short)f2b(a.z); o[3] = (short)f2b(a.w);
    o[4] = (short)f2b(b.x); o[5] = (short)f2b(b.y); o[6] = (short)f2b(b.z); o[7] = (short)f2b(b.w);
    *(bf16x8*)(dst + (size_t)i * 8) = o;
  }
}

// ---------------- weight transpose + downcast: dst[C][R] = bf16(src[R][C]^T) ----------------
__global__ __launch_bounds__(256) void transpose_w(const float* __restrict__ src,
                                                   u16* __restrict__ dst,
                                                   int R, int C) {
  __shared__ float tile[32][33];
  int c0 = blockIdx.x * 32, r0 = blockIdx.y * 32;
  int tx = threadIdx.x, ty = threadIdx.y;
  for (int i = ty; i < 32; i += 8) tile[i][tx] = src[(size_t)(r0 + i) * C + c0 + tx];
  __syncthreads();
  for (int i = ty; i < 32; i += 8) dst[(size_t)(c0 + i) * R + r0 + tx] = f2b(tile[tx][i]);
}

// ---------------- V transpose: qkv V-part [B,N,H,64] -> VT [B*H][64][N] (bf16) ----------------
__global__ __launch_bounds__(256) void transpose_v(const u16* __restrict__ qkv,
                                                   u16* __restrict__ VT) {
  const int N = 2048, TD = 3072, D = 1024;
  int bh = blockIdx.y, n0 = blockIdx.x * 64;
  int b = bh >> 4, h = bh & 15;
  int tid = threadIdx.x;
  __shared__ u16 tl[64][72];
  #pragma unroll
  for (int i = 0; i < 16; ++i) {
    int idx = tid + i * 256;
    int nl = idx >> 6, dd = idx & 63;
    tl[dd][nl] = qkv[(size_t)(b * N + n0 + nl) * TD + 2 * D + h * 64 + dd];
  }
  __syncthreads();
  #pragma unroll
  for (int i = 0; i < 16; ++i) {
    int idx = tid + i * 256;
    int dd = idx >> 6, nl = idx & 63;
    VT[((size_t)bh * 64 + dd) * N + n0 + nl] = tl[dd][nl];
  }
}

// ---------------- 256x256 / BK=64 / 8-wave 8-PHASE bf16 GEMM (m201 template port) ----------------
// LDS: [dbuf = K-tile parity][row-half][128x64] for A and B (128 KB). Per phase:
// {ds_read one C-quadrant's frags | stage ONE half-tile (2x global_load_lds)} ->
// s_barrier -> 16 MFMA (setprio) -> s_barrier. Counted s_waitcnt vmcnt(2) ONLY at
// phases 4 and 8 (gates the next K-tile's reads; newest half-tile stays in flight).
// Stage stream (lag-3, WAR-safe): p1..p8 = A1(k+1),B0(k+1),B1(k+1),A0(k+2),A1(k+2),
// B0(k+2),B1(k+2),A0(k+3) where k = 2*it is the even K-tile computed in phases 1-4.
template <typename OutT>
__global__ __launch_bounds__(512, 1) void gemm8p(
    const u16* __restrict__ A,      // [M][K] bf16
    const u16* __restrict__ BT,     // [N][K] bf16 (K contiguous)
    const float* __restrict__ bias, // [N] fp32
    OutT* __restrict__ C,           // [M][N]
    int M, int N, int K, int nn) {
  __shared__ alignas(16) u16 As[2][2][128 * 64];
  __shared__ alignas(16) u16 Bs[2][2][128 * 64];

  const int nwg = gridDim.x, cpx = nwg >> 3, id0 = blockIdx.x;
  const int swz = (id0 & 7) * cpx + (id0 >> 3);
  const int mi = swz / nn, ni = swz % nn;
  const int m0 = mi * 256, n0 = ni * 256;

  const int t = threadIdx.x;            // 0..511
  const int wid = t >> 6, lane = t & 63;
  const int wr = wid >> 2, wc = wid & 3; // 2M x 4N waves; wave C = 128x64
  const int rlo = lane & 15, g = lane >> 4;
  const int swb = (rlo & 4) ? 32 : 0;    // st_16x32 read-side swizzle bit

  // staging: half-tile = 128 rows x 64 K (16KB) = 512 thr x 2 chunks x 16B.
  // source pre-swizzled (same involution as read side): cs = t ^ (((t>>5)&1)<<1)
  const int cs = t ^ (((t >> 5) & 1) << 1);
  const int sr = cs >> 3, sc8 = (cs & 7) * 8;
  const u16* aSH[2] = {A + (size_t)(m0 + sr) * K + sc8,
                       A + (size_t)(m0 + 128 + sr) * K + sc8};
  const u16* bSH[2] = {BT + (size_t)(n0 + sr) * K + sc8,
                       BT + (size_t)(n0 + 128 + sr) * K + sc8};
  const size_t rowK64 = (size_t)64 * K;

  f32x4 acc[8][4] = {};
  bf16x8 a[4][2], b[2][2];
  const int NT = K >> 6;   // BK=64 K-tiles

#define BAR() __builtin_amdgcn_s_barrier()
#define VM2() asm volatile("s_waitcnt vmcnt(2)" ::: "memory")
#define VM0() asm volatile("s_waitcnt vmcnt(0)" ::: "memory")
#define STAGE_A(h, jt) do { if ((jt) < NT) { const size_t ko_ = (size_t)(jt) * 64; \
    STG(aSH[h] + ko_, &As[(jt) & 1][h][t * 8]); \
    STG(aSH[h] + ko_ + rowK64, &As[(jt) & 1][h][(t + 512) * 8]); } } while (0)
#define STAGE_B(h, jt) do { if ((jt) < NT) { const size_t ko_ = (size_t)(jt) * 64; \
    STG(bSH[h] + ko_, &Bs[(jt) & 1][h][t * 8]); \
    STG(bSH[h] + ko_ + rowK64, &Bs[(jt) & 1][h][(t + 512) * 8]); } } while (0)
#define RDA(buf, mh) _Pragma("unroll") for (int fr = 0; fr < 4; ++fr) \
    _Pragma("unroll") for (int kc = 0; kc < 2; ++kc) { \
      const int r_ = (mh) * 64 + fr * 16 + rlo; \
      a[fr][kc] = *(const bf16x8*)((const char*)&As[buf][wr][0] + \
                                   (((r_ * 64 + kc * 32 + g * 8) * 2) ^ swb)); }
#define RDB(buf, nh) _Pragma("unroll") for (int fn = 0; fn < 2; ++fn) \
    _Pragma("unroll") for (int kc = 0; kc < 2; ++kc) { \
      const int r_ = (wc & 1) * 64 + (nh) * 32 + fn * 16 + rlo; \
      b[fn][kc] = *(const bf16x8*)((const char*)&Bs[buf][wc >> 1][0] + \
                                   (((r_ * 64 + kc * 32 + g * 8) * 2) ^ swb)); }
#define MM(mh, nh) __builtin_amdgcn_s_setprio(1); \
    _Pragma("unroll") for (int fr = 0; fr < 4; ++fr) \
      _Pragma("unroll") for (int fn = 0; fn < 2; ++fn) { \
        f32x4 v_ = acc[(mh) * 4 + fr][(nh) * 2 + fn]; \
        v_ = __builtin_amdgcn_mfma_f32_16x16x32_bf16(a[fr][0], b[fn][0], v_, 0, 0, 0); \
        v_ = __builtin_amdgcn_mfma_f32_16x16x32_bf16(a[fr][1], b[fn][1], v_, 0, 0, 0); \
        acc[(mh) * 4 + fr][(nh) * 2 + fn] = v_; } \
    __builtin_amdgcn_s_setprio(0)

  // prologue: K-tile 0 (4 halves) + A0(1); gate K-tile 0 (allow A0(1) in flight)
  STAGE_A(0, 0); STAGE_A(1, 0); STAGE_B(0, 0); STAGE_B(1, 0); STAGE_A(0, 1);
  VM2(); BAR();

  const int NI = NT >> 1;
  #pragma unroll 1
  for (int it = 0; it < NI; ++it) {
    const int kt1 = 2 * it + 1;
    // p1: quadrant (0,0) of even K-tile (buf 0)
    RDA(0, 0) RDB(0, 0)
    STAGE_A(1, kt1);
    BAR(); MM(0, 0); BAR();
    // p2: (0,1)
    RDB(0, 1)
    STAGE_B(0, kt1);
    BAR(); MM(0, 1); BAR();
    // p3: (1,1)
    RDA(0, 1)
    STAGE_B(1, kt1);
    BAR(); MM(1, 1); BAR();
    // p4: (1,0); GATE odd K-tile
    RDB(0, 0)
    STAGE_A(0, kt1 + 1);
    if (kt1 + 1 < NT) { VM2(); } else { VM0(); }
    BAR(); MM(1, 0); BAR();
    // p5: (0,0) of odd K-tile (buf 1)
    RDA(1, 0) RDB(1, 0)
    STAGE_A(1, kt1 + 1);
    BAR(); MM(0, 0); BAR();
    // p6: (0,1)
    RDB(1, 1)
    STAGE_B(0, kt1 + 1);
    BAR(); MM(0, 1); BAR();
    // p7: (1,1)
    RDA(1, 1)
    STAGE_B(1, kt1 + 1);
    BAR(); MM(1, 1); BAR();
    // p8: (1,0); GATE next even K-tile (skip on last iteration)
    RDB(1, 0)
    STAGE_A(0, kt1 + 2);
    if (kt1 + 1 < NT) { if (kt1 + 2 < NT) { VM2(); } else { VM0(); } }
    BAR(); MM(1, 0); BAR();
  }
#undef BAR
#undef VM2
#undef VM0
#undef STAGE_A
#undef STAGE_B
#undef RDA
#undef RDB
#undef MM

  // epilogue: bias + store (r10-verified mapping)
  #pragma unroll
  for (int nr = 0; nr < 4; ++nr) {
    const int col = n0 + wc * 64 + nr * 16 + rlo;
    const float bv = bias[col];
    #pragma unroll
    for (int mr = 0; mr < 8; ++mr) {
      const int row = m0 + wr * 128 + mr * 16 + g * 4;
      #pragma unroll
      for (int i = 0; i < 4; ++i) {
        float r = acc[mr][nr][i] + bv;
        if constexpr (sizeof(OutT) == 2)
          C[(size_t)(row + i) * N + col] = (OutT)f2b(r);
        else
          C[(size_t)(row + i) * N + col] = (OutT)r;
      }
    }
  }
}

// ---------------- 256x128 / BK=32 / 4-wave bf16 GEMM (r13; used for proj) ----------------
template <typename OutT>
__global__ __launch_bounds__(256, 2) void gemm256(
    const u16* __restrict__ A,      // [M][K] bf16
    const u16* __restrict__ BT,     // [N][K] bf16 (K contiguous)
    const float* __restrict__ bias, // [N] fp32
    OutT* __restrict__ C,           // [M][N]
    int M, int N, int K, int nn) {
  __shared__ alignas(16) u16 As[3][256 * 32];
  __shared__ alignas(16) u16 Bs[3][128 * 32];

  const int nwg = gridDim.x, cpx = nwg >> 3, id0 = blockIdx.x;
  const int swz = (id0 & 7) * cpx + (id0 >> 3);
  const int mi = swz / nn, ni = swz % nn;
  const int m0 = mi * 256, n0 = ni * 128;

  const int t = threadIdx.x;
  const int wid = t >> 6, lane = t & 63;
  const int wr = wid >> 1, wc = wid & 1;
  const int rlo = lane & 15, g = lane >> 4;

  const u16* aSrc[4];
  const u16* bSrc[2];
  int dA[4], dB[2];
  #pragma unroll
  for (int k = 0; k < 4; ++k) {
    const int c = t + 256 * k, cs = c ^ ((c >> 3) & 3);
    aSrc[k] = A + (size_t)(m0 + (cs >> 2)) * K + (cs & 3) * 8;
    dA[k] = c * 8;
  }
  #pragma unroll
  for (int k = 0; k < 2; ++k) {
    const int c = t + 256 * k, cs = c ^ ((c >> 3) & 3);
    bSrc[k] = BT + (size_t)(n0 + (cs >> 2)) * K + (cs & 3) * 8;
    dB[k] = c * 8;
  }

  f32x4 acc[8][4] = {};
  const int NT = K >> 5;

  #pragma unroll
  for (int k = 0; k < 4; ++k) STG(aSrc[k], &As[0][dA[k]]);
  #pragma unroll
  for (int k = 0; k < 2; ++k) STG(bSrc[k], &Bs[0][dB[k]]);
  #pragma unroll
  for (int k = 0; k < 4; ++k) STG(aSrc[k] + 32, &As[1][dA[k]]);
  #pragma unroll
  for (int k = 0; k < 2; ++k) STG(bSrc[k] + 32, &Bs[1][dB[k]]);

  int rb = 0, sb = 2;
  for (int kt = 0; kt < NT; ++kt) {
    __builtin_amdgcn_s_barrier();

    if (kt + 2 < NT) {
      const int ko = (kt + 2) * 32;
      #pragma unroll
      for (int k = 0; k < 4; ++k) STG(aSrc[k] + ko, &As[sb][dA[k]]);
      #pragma unroll
      for (int k = 0; k < 2; ++k) STG(bSrc[k] + ko, &Bs[sb][dB[k]]);
    }

    if (kt + 2 < NT)      asm volatile("s_waitcnt vmcnt(12)" ::: "memory");
    else if (kt + 1 < NT) asm volatile("s_waitcnt vmcnt(6)" ::: "memory");
    else                  asm volatile("s_waitcnt vmcnt(0)" ::: "memory");
    __builtin_amdgcn_s_barrier();

    const char* aB = (const char*)&As[rb][0];
    const char* bB = (const char*)&Bs[rb][0];
    bf16x8 a[8], b[4];
    #pragma unroll
    for (int fr = 0; fr < 8; ++fr) {
      const int r_ = wr * 128 + fr * 16 + rlo;
      a[fr] = *(const bf16x8*)(aB + (r_ * 64 + ((g ^ ((r_ >> 1) & 3)) << 4)));
    }
    #pragma unroll
    for (int fn = 0; fn < 4; ++fn) {
      const int r_ = wc * 64 + fn * 16 + rlo;
      b[fn] = *(const bf16x8*)(bB + (r_ * 64 + ((g ^ ((r_ >> 1) & 3)) << 4)));
    }
    __builtin_amdgcn_s_setprio(1);
    #pragma unroll
    for (int fr = 0; fr < 8; ++fr)
      #pragma unroll
      for (int fn = 0; fn < 4; ++fn)
        acc[fr][fn] = __builtin_amdgcn_mfma_f32_16x16x32_bf16(a[fr], b[fn], acc[fr][fn], 0, 0, 0);
    __builtin_amdgcn_s_setprio(0);

    rb = (rb == 2) ? 0 : rb + 1;
    sb = (sb == 2) ? 0 : sb + 1;
  }

  #pragma unroll
  for (int fn = 0; fn < 4; ++fn) {
    const int col = n0 + wc * 64 + fn * 16 + rlo;
    const float bv = bias[col];
    #pragma unroll
    for (int fr = 0; fr < 8; ++fr) {
      const int row = m0 + wr * 128 + fr * 16 + g * 4;
      #pragma unroll
      for (int i = 0; i < 4; ++i) {
        float r = acc[fr][fn][i] + bv;
        if constexpr (sizeof(OutT) == 2)
          C[(size_t)(row + i) * N + col] = (OutT)f2b(r);
        else
          C[(size_t)(row + i) * N + col] = (OutT)r;
      }
    }
  }
}

// ---------------- causal flash attention: waves split over (q-half x kv-subtile) ----------------
__global__ __launch_bounds__(256, 2) void attn_fwd(
    const u16* __restrict__ qkv,  // [B*N][3072] bf16; Q col 0, K col 1024
    const u16* __restrict__ VT,   // [B*H][64][2048] bf16
    u16* __restrict__ O) {        // [B*N][1024] bf16
  const int N = 2048, TD = 3072, D = 1024;
  const int bid = blockIdx.x;
  const int qp = bid >> 6, bh = bid & 63;
  const int b = bh >> 4, h = bh & 15;
  const int t = threadIdx.x, w = t >> 6, lane = t & 63;
  const int l31 = lane & 31, hi = lane >> 5;
  const int qh = w >> 1, st = w & 1;

  __shared__ alignas(16) u16 pool16[2][64 * 64];
  __shared__ float rsLds[2][32];
  float* poolf = (float*)&pool16[0][0];

  const int c1 = t, c2 = t + 256;
  const int r1 = c1 >> 3, sc1 = ((c1 & 7) ^ (r1 & 7)) * 8;
  const int r2 = c2 >> 3, sc2 = ((c2 & 7) ^ (r2 & 7)) * 8;
  const u16* kbase = qkv + (size_t)(b * N) * TD + D + h * 64;
  const u16* vbase = VT + (size_t)bh * 64 * N;

  const float L2E = 1.44269504089f;
  const float NSH = -23.0830992f;  // -16*log2(e): p = exp2(s*L2E + NSH) = exp(s-16)

  for (int pass = 0; pass < 2; ++pass) {
    const int qt = pass ? (15 - qp) : qp;
    const int qbw = qt * 128 + qh * 64;

    bf16x8 qf[2][4];
    #pragma unroll
    for (int qs = 0; qs < 2; ++qs) {
      const u16* qp_ = qkv + ((size_t)(b * N) + qbw + qs * 32 + l31) * TD + h * 64 + hi * 8;
      #pragma unroll
      for (int c = 0; c < 4; ++c) {
        bf16x8 v = *(const bf16x8*)(qp_ + c * 16);
        #pragma unroll
        for (int j = 0; j < 8; ++j)
          v[j] = (short)f2b(b2f((u16)v[j]) * 0.125f);
        qf[qs][c] = v;
      }
    }

    f32x16 o_acc[2][2] = {};
    float psum[2] = {0.f, 0.f};
    const int jend = qt * 128 + 64;

    for (int j0 = 0; j0 <= jend; j0 += 64) {
      STG(kbase + (size_t)(j0 + r1) * TD + sc1, &pool16[0][c1 * 8]);
      STG(kbase + (size_t)(j0 + r2) * TD + sc2, &pool16[0][c2 * 8]);
      STG(vbase + (size_t)r1 * N + j0 + sc1, &pool16[1][c1 * 8]);
      STG(vbase + (size_t)r2 * N + j0 + sc2, &pool16[1][c2 * 8]);
      __syncthreads();

      const int sb2 = j0 + st * 32;
      if (sb2 <= qbw + 63) {
        bf16x8 kf[4];
        {
          const int row = st * 32 + l31, sw = (row & 7) << 3;
          #pragma unroll
          for (int c = 0; c < 4; ++c)
            kf[c] = *(const bf16x8*)&pool16[0][row * 64 + ((c * 16 + hi * 8) ^ sw)];
        }
        bf16x8 vf[2][2];
        #pragma unroll
        for (int dt = 0; dt < 2; ++dt) {
          const int row = dt * 32 + l31, sw = (row & 7) << 3;
          #pragma unroll
          for (int kc = 0; kc < 2; ++kc)
            vf[kc][dt] = *(const bf16x8*)&pool16[1][row * 64 + ((st * 32 + kc * 16 + hi * 8) ^ sw)];
        }

        #pragma unroll
        for (int qs = 0; qs < 2; ++qs) {
          if (qs == 0 && sb2 > qbw + 31) continue;
          const int qr = qbw + qs * 32 + l31;
          f32x16 S = {};
          __builtin_amdgcn_s_setprio(1);
          #pragma unroll
          for (int c = 0; c < 4; ++c)
            S = __builtin_amdgcn_mfma_f32_32x32x16_bf16(kf[c], qf[qs][c], S, 0, 0, 0);
          __builtin_amdgcn_s_setprio(0);
          if (sb2 + 31 > qbw + qs * 32) {
            const int kvb = sb2 + 4 * hi;
            #pragma unroll
            for (int r = 0; r < 16; ++r)
              if (kvb + (r & 3) + 8 * (r >> 2) > qr) S[r] = -1e30f;
          }
          float p[16];
          #pragma unroll
          for (int r = 0; r < 16; ++r) p[r] = EXP2F(fmaf(S[r], L2E, NSH));
          float ps = 0.f;
          #pragma unroll
          for (int r = 0; r < 16; ++r) ps += p[r];
          psum[qs] += ps;
          u32 wq[8];
          #pragma unroll
          for (int i = 0; i < 8; ++i) wq[i] = cvt_pk_bf16(p[2 * i], p[2 * i + 1]);
          permswap(wq[0], wq[2]); permswap(wq[1], wq[3]);
          permswap(wq[4], wq[6]); permswap(wq[5], wq[7]);
          union { u32 u[4]; bf16x8 v; } pa0, pa1;
          pa0.u[0] = wq[0]; pa0.u[1] = wq[1]; pa0.u[2] = wq[2]; pa0.u[3] = wq[3];
          pa1.u[0] = wq[4]; pa1.u[1] = wq[5]; pa1.u[2] = wq[6]; pa1.u[3] = wq[7];
          __builtin_amdgcn_s_setprio(1);
          #pragma unroll
          for (int dt = 0; dt < 2; ++dt) {
            o_acc[qs][dt] = __builtin_amdgcn_mfma_f32_32x32x16_bf16(pa0.v, vf[0][dt], o_acc[qs][dt], 0, 0, 0);
            o_acc[qs][dt] = __builtin_amdgcn_mfma_f32_32x32x16_bf16(pa1.v, vf[1][dt], o_acc[qs][dt], 0, 0, 0);
          }
          __builtin_amdgcn_s_setprio(0);
        }
      }
      __syncthreads();
    }

    float rsown[2];
    #pragma unroll
    for (int qs = 0; qs < 2; ++qs)
      rsown[qs] = psum[qs] + __shfl_xor(psum[qs], 32, 64);

    #pragma unroll
    for (int qs = 0; qs < 2; ++qs) {
      if (st != qs) {
        #pragma unroll
        for (int dt = 0; dt < 2; ++dt)
          #pragma unroll
          for (int r = 0; r < 16; ++r)
            poolf[qh * 2048 + (dt * 16 + r) * 64 + lane] = o_acc[qs][dt][r];
        rsLds[qh][l31] = rsown[qs];
      }
      __syncthreads();
      if (st == qs) {
        const float inv = 1.0f / (rsown[qs] + rsLds[qh][l31]);
        #pragma unroll
        for (int r = 0; r < 16; ++r) {
          const int qrow = (r & 3) + 8 * (r >> 2) + 4 * hi;
          const float invq = __shfl(inv, qrow, 64);
          const int q = qbw + qs * 32 + qrow;
          #pragma unroll
          for (int dt = 0; dt < 2; ++dt) {
            const float val = o_acc[qs][dt][r] + poolf[qh * 2048 + (dt * 16 + r) * 64 + lane];
            O[((size_t)(b * N) + q) * D + h * 64 + dt * 32 + l31] = f2b(val * invq);
          }
        }
      }
      __syncthreads();
    }
  }
}

extern "C" void kernel_launch(void* const* d_in, const int* in_sizes, int n_in,
                              void* d_out, int out_size, void* d_ws, size_t ws_size,
                              hipStream_t stream) {
  const float* x     = (const float*)d_in[0];
  // d_in[1] = causal_mask (fp32): handled structurally, unused
  const float* Wqkv  = (const float*)d_in[2];
  const float* bqkv  = (const float*)d_in[3];
  const float* Wproj = (const float*)d_in[4];
  const float* bproj = (const float*)d_in[5];
  float* out = (float*)d_out;

  const int B = 4, N = 2048, D = 1024, H = 16;
  const int BN = B * N;    // 8192
  const int TD = 3 * D;    // 3072

  char* ws = (char*)d_ws;
  u16* qkv    = (u16*)(ws);                      // 50,331,648 B
  u16* vt     = (u16*)(ws + 50331648);           // 16,777,216 B
  u16* aout   = (u16*)(ws + 67108864);           // 16,777,216 B
  u16* wqkvT  = (u16*)(ws + 83886080);           //  6,291,456 B
  u16* wprojT = (u16*)(ws + 90177536);           //  2,097,152 B
  u16* xb     = (u16*)(ws + 92274688);           // 16,777,216 B

  // 1) downcast x to bf16
  cast_f32_bf16<<<2048, 256, 0, stream>>>(x, xb, BN * D / 8);
  // 2) weight transposes + downcast (K-contiguous B operands)
  transpose_w<<<dim3(TD / 32, D / 32), dim3(32, 8), 0, stream>>>(Wqkv, wqkvT, D, TD);
  transpose_w<<<dim3(D / 32, D / 32), dim3(32, 8), 0, stream>>>(Wproj, wprojT, D, D);
  // 3) QKV projection: 8-phase 256x256, 384 blocks (32 m x 12 n)
  gemm8p<u16><<<384, 512, 0, stream>>>(xb, wqkvT, bqkv, qkv, BN, TD, D, 12);
  // 4) V transpose per (b,h)
  transpose_v<<<dim3(N / 64, B * H), 256, 0, stream>>>(qkv, vt);
  // 5) causal flash attention, (q-half x kv-subtile) wave split (8 qp x 64 bh)
  attn_fwd<<<512, 256, 0, stream>>>(qkv, vt, aout);
  // 6) output projection: 256 blocks (32 m x 8 n), fp32 out + bias
  gemm256<float><<<256, 256, 0, stream>>>(aout, wprojT, bproj, out, BN, D, D, 8);
}

// Round 15
// 185.910 us; speedup vs baseline: 1.0657x; 1.0657x over previous
//
#include <hip/hip_runtime.h>
#include <hip/hip_bf16.h>

typedef unsigned short u16;
typedef unsigned int u32;
typedef __attribute__((ext_vector_type(8))) short bf16x8;
typedef __attribute__((ext_vector_type(4))) float f32x4;
typedef __attribute__((ext_vector_type(16))) float f32x16;

#define AS1(p) ((const __attribute__((address_space(1))) void*)(p))
#define AS3(p) ((__attribute__((address_space(3))) void*)(p))
#define STG(src, dst) __builtin_amdgcn_global_load_lds(AS1(src), AS3(dst), 16, 0, 0)

#if __has_builtin(__builtin_amdgcn_exp2f)
#define EXP2F(x) __builtin_amdgcn_exp2f(x)
#else
#define EXP2F(x) exp2f(x)
#endif

static __device__ __forceinline__ float b2f(u16 u) {
  union { unsigned int i; float f; } v; v.i = ((unsigned int)u) << 16; return v.f;
}
static __device__ __forceinline__ u16 f2b(float f) {
  union { float f; unsigned int i; } v; v.f = f;
  unsigned int r = v.i + 0x7FFFu + ((v.i >> 16) & 1u);
  return (u16)(r >> 16);
}
static __device__ __forceinline__ u32 cvt_pk_bf16(float lo, float hi) {
  u32 r;
  asm("v_cvt_pk_bf16_f32 %0, %1, %2" : "=v"(r) : "v"(lo), "v"(hi));
  return r;
}
static __device__ __forceinline__ void permswap(u32& a, u32& b) {
  asm("v_permlane32_swap_b32 %0, %1" : "+v"(a), "+v"(b));
}

// ---------------- fp32 -> bf16 cast (vectorized, grid-stride) ----------------
__global__ __launch_bounds__(256) void cast_f32_bf16(const float* __restrict__ src,
                                                     u16* __restrict__ dst, int n8) {
  int stride = gridDim.x * blockDim.x;
  for (int i = blockIdx.x * blockDim.x + threadIdx.x; i < n8; i += stride) {
    const float4* s = (const float4*)(src + (size_t)i * 8);
    float4 a = s[0], b = s[1];
    bf16x8 o;
    o[0] = (short)f2b(a.x); o[1] = (short)f2b(a.y); o[2] = (short)f2b(a.z); o[3] = (short)f2b(a.w);
    o[4] = (short)f2b(b.x); o[5] = (short)f2b(b.y); o[6] = (short)f2b(b.z); o[7] = (short)f2b(b.w);
    *(bf16x8*)(dst + (size_t)i * 8) = o;
  }
}

// ---------------- weight transpose + downcast: dst[C][R] = bf16(src[R][C]^T) ----------------
__global__ __launch_bounds__(256) void transpose_w(const float* __restrict__ src,
                                                   u16* __restrict__ dst,
                                                   int R, int C) {
  __shared__ float tile[32][33];
  int c0 = blockIdx.x * 32, r0 = blockIdx.y * 32;
  int tx = threadIdx.x, ty = threadIdx.y;
  for (int i = ty; i < 32; i += 8) tile[i][tx] = src[(size_t)(r0 + i) * C + c0 + tx];
  __syncthreads();
  for (int i = ty; i < 32; i += 8) dst[(size_t)(c0 + i) * R + r0 + tx] = f2b(tile[tx][i]);
}

// ---------------- V transpose: qkv V-part [B,N,H,64] -> VT [B*H][64][N] (bf16) ----------------
__global__ __launch_bounds__(256) void transpose_v(const u16* __restrict__ qkv,
                                                   u16* __restrict__ VT) {
  const int N = 2048, TD = 3072, D = 1024;
  int bh = blockIdx.y, n0 = blockIdx.x * 64;
  int b = bh >> 4, h = bh & 15;
  int tid = threadIdx.x;
  __shared__ u16 tl[64][72];
  #pragma unroll
  for (int i = 0; i < 16; ++i) {
    int idx = tid + i * 256;
    int nl = idx >> 6, dd = idx & 63;
    tl[dd][nl] = qkv[(size_t)(b * N + n0 + nl) * TD + 2 * D + h * 64 + dd];
  }
  __syncthreads();
  #pragma unroll
  for (int i = 0; i < 16; ++i) {
    int idx = tid + i * 256;
    int dd = idx >> 6, nl = idx & 63;
    VT[((size_t)bh * 64 + dd) * N + n0 + nl] = tl[dd][nl];
  }
}

// ---------------- m97-structure bf16 GEMM (r9, measured best: QKV 80.8us) ----------------
template <typename OutT>
__global__ __launch_bounds__(256) void gemm_bt_bias(
    const u16* __restrict__ A,     // [M][K] bf16
    const u16* __restrict__ BT,    // [N][K] bf16 (K contiguous)
    const float* __restrict__ bias,// [N] fp32
    OutT* __restrict__ C,          // [M][N]
    int M, int N, int K) {
  __shared__ alignas(16) u16 Als[128 * 32];
  __shared__ alignas(16) u16 Bls[128 * 32];
  const int m0 = blockIdx.x * 128, n0 = blockIdx.y * 128;
  const int t = threadIdx.x;
  const int w = t >> 6, lane = t & 63;
  const int wr = w >> 1, wc = w & 1;
  const int rlo = lane & 15, g = lane >> 4;

  f32x4 acc[4][4] = {};

  const int r0 = t >> 2;
  const int c0 = (t & 3) << 3;
  const u16* aSrc = A + (size_t)(m0 + r0) * K + c0;
  const u16* bSrc = BT + (size_t)(n0 + r0) * K + c0;

  for (int k0 = 0; k0 < K; k0 += 32) {
    __builtin_amdgcn_global_load_lds(AS1(aSrc + k0), AS3(&Als[t * 8]), 16, 0, 0);
    __builtin_amdgcn_global_load_lds(AS1(aSrc + (size_t)64 * K + k0), AS3(&Als[(t + 256) * 8]), 16, 0, 0);
    __builtin_amdgcn_global_load_lds(AS1(bSrc + k0), AS3(&Bls[t * 8]), 16, 0, 0);
    __builtin_amdgcn_global_load_lds(AS1(bSrc + (size_t)64 * K + k0), AS3(&Bls[(t + 256) * 8]), 16, 0, 0);
    __syncthreads();

    bf16x8 a[4], b[4];
    #pragma unroll
    for (int m = 0; m < 4; ++m)
      a[m] = *(const bf16x8*)&Als[(wr * 64 + m * 16 + rlo) * 32 + g * 8];
    #pragma unroll
    for (int n = 0; n < 4; ++n)
      b[n] = *(const bf16x8*)&Bls[(wc * 64 + n * 16 + rlo) * 32 + g * 8];
    #pragma unroll
    for (int m = 0; m < 4; ++m)
      #pragma unroll
      for (int n = 0; n < 4; ++n)
        acc[m][n] = __builtin_amdgcn_mfma_f32_16x16x32_bf16(a[m], b[n], acc[m][n], 0, 0, 0);
    __syncthreads();
  }

  #pragma unroll
  for (int n = 0; n < 4; ++n) {
    const int col = n0 + wc * 64 + n * 16 + rlo;
    const float bv = bias[col];
    #pragma unroll
    for (int m = 0; m < 4; ++m) {
      const int row = m0 + wr * 64 + m * 16 + g * 4;
      #pragma unroll
      for (int i = 0; i < 4; ++i) {
        float r = acc[m][n][i] + bv;
        if constexpr (sizeof(OutT) == 2)
          C[(size_t)(row + i) * N + col] = (OutT)f2b(r);
        else
          C[(size_t)(row + i) * N + col] = (OutT)r;
      }
    }
  }
}

// ---------------- causal flash attention: (q-half x kv-subtile) wave split + DBUF staging ----------------
// grid 512 = 8 qp x 64 bh; sequential paired q-tiles (qp then 15-qp), balanced 34 iters.
// Wave w = (qh=w>>1, st=w&1): 64 q rows, ONE 32-kv subtile -> 8 ds_read_b128/iter.
// K/V double-buffered (32KB): stage(j+1) issued BEFORE compute(j); single __syncthreads
// per tile (its vmcnt(0) drain waits loads issued a full compute-window ago -> hidden).
// Waves (qh,0)/(qh,1) hold partial O for the same q rows -> per-pass LDS reduction.
__global__ __launch_bounds__(256, 2) void attn_fwd(
    const u16* __restrict__ qkv,  // [B*N][3072] bf16; Q col 0, K col 1024
    const u16* __restrict__ VT,   // [B*H][64][2048] bf16
    u16* __restrict__ O) {        // [B*N][1024] bf16
  const int N = 2048, TD = 3072, D = 1024;
  const int bid = blockIdx.x;
  const int qp = bid >> 6, bh = bid & 63;
  const int b = bh >> 4, h = bh & 15;
  const int t = threadIdx.x, w = t >> 6, lane = t & 63;
  const int l31 = lane & 31, hi = lane >> 5;
  const int qh = w >> 1, st = w & 1;

  // [buf][0]=K tile, [buf][1]=V tile; swizzled col ^ ((row&7)<<3). Epilogue reuses as float pool.
  __shared__ alignas(16) u16 pool16[2][2][64 * 64];
  __shared__ float rsLds[2][32];
  float* poolf = (float*)&pool16[0][0][0];

  const int c1 = t, c2 = t + 256;
  const int r1 = c1 >> 3, sc1 = ((c1 & 7) ^ (r1 & 7)) * 8;
  const int r2 = c2 >> 3, sc2 = ((c2 & 7) ^ (r2 & 7)) * 8;
  const u16* kbase = qkv + (size_t)(b * N) * TD + D + h * 64;
  const u16* vbase = VT + (size_t)bh * 64 * N;

#define ASTAGE(buf, j0) do { \
    STG(kbase + (size_t)((j0) + r1) * TD + sc1, &pool16[buf][0][c1 * 8]); \
    STG(kbase + (size_t)((j0) + r2) * TD + sc2, &pool16[buf][0][c2 * 8]); \
    STG(vbase + (size_t)r1 * N + (j0) + sc1, &pool16[buf][1][c1 * 8]); \
    STG(vbase + (size_t)r2 * N + (j0) + sc2, &pool16[buf][1][c2 * 8]); } while (0)

  const float L2E = 1.44269504089f;
  const float NSH = -23.0830992f;  // -16*log2(e): p = exp2(s*L2E + NSH) = exp(s-16)

  for (int pass = 0; pass < 2; ++pass) {
    const int qt = pass ? (15 - qp) : qp;
    const int qbw = qt * 128 + qh * 64;

    bf16x8 qf[2][4];
    #pragma unroll
    for (int qs = 0; qs < 2; ++qs) {
      const u16* qp_ = qkv + ((size_t)(b * N) + qbw + qs * 32 + l31) * TD + h * 64 + hi * 8;
      #pragma unroll
      for (int c = 0; c < 4; ++c) {
        bf16x8 v = *(const bf16x8*)(qp_ + c * 16);
        #pragma unroll
        for (int j = 0; j < 8; ++j)
          v[j] = (short)f2b(b2f((u16)v[j]) * 0.125f);
        qf[qs][c] = v;
      }
    }

    f32x16 o_acc[2][2] = {};
    float psum[2] = {0.f, 0.f};
    const int jend = qt * 128 + 64;

    // prologue: stage tile 0 into buf 0
    ASTAGE(0, 0);
    __syncthreads();

    int cur = 0;
    for (int j0 = 0; j0 <= jend; j0 += 64) {
      // issue next tile's staging into the other buffer (lands during compute)
      if (j0 + 64 <= jend) ASTAGE(cur ^ 1, j0 + 64);

      const int sb2 = j0 + st * 32;
      if (sb2 <= qbw + 63) {
        bf16x8 kf[4];
        {
          const int row = st * 32 + l31, sw = (row & 7) << 3;
          #pragma unroll
          for (int c = 0; c < 4; ++c)
            kf[c] = *(const bf16x8*)&pool16[cur][0][row * 64 + ((c * 16 + hi * 8) ^ sw)];
        }
        bf16x8 vf[2][2];
        #pragma unroll
        for (int dt = 0; dt < 2; ++dt) {
          const int row = dt * 32 + l31, sw = (row & 7) << 3;
          #pragma unroll
          for (int kc = 0; kc < 2; ++kc)
            vf[kc][dt] = *(const bf16x8*)&pool16[cur][1][row * 64 + ((st * 32 + kc * 16 + hi * 8) ^ sw)];
        }

        #pragma unroll
        for (int qs = 0; qs < 2; ++qs) {
          if (qs == 0 && sb2 > qbw + 31) continue;
          const int qr = qbw + qs * 32 + l31;
          f32x16 S = {};
          __builtin_amdgcn_s_setprio(1);
          #pragma unroll
          for (int c = 0; c < 4; ++c)
            S = __builtin_amdgcn_mfma_f32_32x32x16_bf16(kf[c], qf[qs][c], S, 0, 0, 0);
          __builtin_amdgcn_s_setprio(0);
          if (sb2 + 31 > qbw + qs * 32) {
            const int kvb = sb2 + 4 * hi;
            #pragma unroll
            for (int r = 0; r < 16; ++r)
              if (kvb + (r & 3) + 8 * (r >> 2) > qr) S[r] = -1e30f;
          }
          float p[16];
          #pragma unroll
          for (int r = 0; r < 16; ++r) p[r] = EXP2F(fmaf(S[r], L2E, NSH));
          float ps = 0.f;
          #pragma unroll
          for (int r = 0; r < 16; ++r) ps += p[r];
          psum[qs] += ps;
          u32 wq[8];
          #pragma unroll
          for (int i = 0; i < 8; ++i) wq[i] = cvt_pk_bf16(p[2 * i], p[2 * i + 1]);
          permswap(wq[0], wq[2]); permswap(wq[1], wq[3]);
          permswap(wq[4], wq[6]); permswap(wq[5], wq[7]);
          union { u32 u[4]; bf16x8 v; } pa0, pa1;
          pa0.u[0] = wq[0]; pa0.u[1] = wq[1]; pa0.u[2] = wq[2]; pa0.u[3] = wq[3];
          pa1.u[0] = wq[4]; pa1.u[1] = wq[5]; pa1.u[2] = wq[6]; pa1.u[3] = wq[7];
          __builtin_amdgcn_s_setprio(1);
          #pragma unroll
          for (int dt = 0; dt < 2; ++dt) {
            o_acc[qs][dt] = __builtin_amdgcn_mfma_f32_32x32x16_bf16(pa0.v, vf[0][dt], o_acc[qs][dt], 0, 0, 0);
            o_acc[qs][dt] = __builtin_amdgcn_mfma_f32_32x32x16_bf16(pa1.v, vf[1][dt], o_acc[qs][dt], 0, 0, 0);
          }
          __builtin_amdgcn_s_setprio(0);
        }
      }
      __syncthreads();  // drains in-flight stage (issued before compute) + syncs waves
      cur ^= 1;
    }

    // ---- epilogue: combine st=0/st=1 partials per (qh, qs) via LDS ----
    float rsown[2];
    #pragma unroll
    for (int qs = 0; qs < 2; ++qs)
      rsown[qs] = psum[qs] + __shfl_xor(psum[qs], 32, 64);

    #pragma unroll
    for (int qs = 0; qs < 2; ++qs) {
      if (st != qs) {
        #pragma unroll
        for (int dt = 0; dt < 2; ++dt)
          #pragma unroll
          for (int r = 0; r < 16; ++r)
            poolf[qh * 2048 + (dt * 16 + r) * 64 + lane] = o_acc[qs][dt][r];
        rsLds[qh][l31] = rsown[qs];
      }
      __syncthreads();
      if (st == qs) {
        const float inv = 1.0f / (rsown[qs] + rsLds[qh][l31]);
        #pragma unroll
        for (int r = 0; r < 16; ++r) {
          const int qrow = (r & 3) + 8 * (r >> 2) + 4 * hi;
          const float invq = __shfl(inv, qrow, 64);
          const int q = qbw + qs * 32 + qrow;
          #pragma unroll
          for (int dt = 0; dt < 2; ++dt) {
            const float val = o_acc[qs][dt][r] + poolf[qh * 2048 + (dt * 16 + r) * 64 + lane];
            O[((size_t)(b * N) + q) * D + h * 64 + dt * 32 + l31] = f2b(val * invq);
          }
        }
      }
      __syncthreads();
    }
  }
#undef ASTAGE
}

extern "C" void kernel_launch(void* const* d_in, const int* in_sizes, int n_in,
                              void* d_out, int out_size, void* d_ws, size_t ws_size,
                              hipStream_t stream) {
  const float* x     = (const float*)d_in[0];
  // d_in[1] = causal_mask (fp32): handled structurally, unused
  const float* Wqkv  = (const float*)d_in[2];
  const float* bqkv  = (const float*)d_in[3];
  const float* Wproj = (const float*)d_in[4];
  const float* bproj = (const float*)d_in[5];
  float* out = (float*)d_out;

  const int B = 4, N = 2048, D = 1024, H = 16;
  const int BN = B * N;    // 8192
  const int TD = 3 * D;    // 3072

  char* ws = (char*)d_ws;
  u16* qkv    = (u16*)(ws);                      // 50,331,648 B
  u16* vt     = (u16*)(ws + 50331648);           // 16,777,216 B
  u16* aout   = (u16*)(ws + 67108864);           // 16,777,216 B
  u16* wqkvT  = (u16*)(ws + 83886080);           //  6,291,456 B
  u16* wprojT = (u16*)(ws + 90177536);           //  2,097,152 B
  u16* xb     = (u16*)(ws + 92274688);           // 16,777,216 B

  // 1) downcast x to bf16
  cast_f32_bf16<<<2048, 256, 0, stream>>>(x, xb, BN * D / 8);
  // 2) weight transposes + downcast (K-contiguous B operands)
  transpose_w<<<dim3(TD / 32, D / 32), dim3(32, 8), 0, stream>>>(Wqkv, wqkvT, D, TD);
  transpose_w<<<dim3(D / 32, D / 32), dim3(32, 8), 0, stream>>>(Wproj, wprojT, D, D);
  // 3) QKV projection (r9 structure, measured best)
  gemm_bt_bias<u16><<<dim3(BN / 128, TD / 128), 256, 0, stream>>>(xb, wqkvT, bqkv, qkv, BN, TD, D);
  // 4) V transpose per (b,h)
  transpose_v<<<dim3(N / 64, B * H), 256, 0, stream>>>(qkv, vt);
  // 5) causal flash attention, (q-half x kv-subtile) wave split + dbuf staging
  attn_fwd<<<512, 256, 0, stream>>>(qkv, vt, aout);
  // 6) output projection (fp32 out + bias)
  gemm_bt_bias<float><<<dim3(BN / 128, D / 128), 256, 0, stream>>>(aout, wprojT, bproj, out, BN, D, D);
}

// Round 16
// 178.631 us; speedup vs baseline: 1.1091x; 1.0408x over previous
//
#include <hip/hip_runtime.h>
#include <hip/hip_bf16.h>

typedef unsigned short u16;
typedef unsigned int u32;
typedef __attribute__((ext_vector_type(8))) short bf16x8;
typedef __attribute__((ext_vector_type(4))) float f32x4;
typedef __attribute__((ext_vector_type(16))) float f32x16;

#define AS1(p) ((const __attribute__((address_space(1))) void*)(p))
#define AS3(p) ((__attribute__((address_space(3))) void*)(p))
#define STG(src, dst) __builtin_amdgcn_global_load_lds(AS1(src), AS3(dst), 16, 0, 0)

#if __has_builtin(__builtin_amdgcn_exp2f)
#define EXP2F(x) __builtin_amdgcn_exp2f(x)
#else
#define EXP2F(x) exp2f(x)
#endif

static __device__ __forceinline__ float b2f(u16 u) {
  union { unsigned int i; float f; } v; v.i = ((unsigned int)u) << 16; return v.f;
}
static __device__ __forceinline__ u16 f2b(float f) {
  union { float f; unsigned int i; } v; v.f = f;
  unsigned int r = v.i + 0x7FFFu + ((v.i >> 16) & 1u);
  return (u16)(r >> 16);
}
static __device__ __forceinline__ u32 cvt_pk_bf16(float lo, float hi) {
  u32 r;
  asm("v_cvt_pk_bf16_f32 %0, %1, %2" : "=v"(r) : "v"(lo), "v"(hi));
  return r;
}
static __device__ __forceinline__ void permswap(u32& a, u32& b) {
  asm("v_permlane32_swap_b32 %0, %1" : "+v"(a), "+v"(b));
}

// ---------------- fused prep: x cast (blocks 0..2047) + Wqkv^T (2048..5119) + Wproj^T (5120..6143) ----------------
__global__ __launch_bounds__(256) void prep(const float* __restrict__ x, u16* __restrict__ xb,
                                            const float* __restrict__ Wqkv, u16* __restrict__ wqkvT,
                                            const float* __restrict__ Wproj, u16* __restrict__ wprojT) {
  __shared__ float tile[32][33];
  const int bid = blockIdx.x, t = threadIdx.x;
  if (bid < 2048) {
    const int n8 = 8192 * 1024 / 8;
    for (int i = bid * 256 + t; i < n8; i += 2048 * 256) {
      const float4* s = (const float4*)(x + (size_t)i * 8);
      float4 a = s[0], b = s[1];
      bf16x8 o;
      o[0] = (short)f2b(a.x); o[1] = (short)f2b(a.y); o[2] = (short)f2b(a.z); o[3] = (short)f2b(a.w);
      o[4] = (short)f2b(b.x); o[5] = (short)f2b(b.y); o[6] = (short)f2b(b.z); o[7] = (short)f2b(b.w);
      *(bf16x8*)(xb + (size_t)i * 8) = o;
    }
  } else {
    const float* src; u16* dst; int R, C, cx, ry;
    if (bid < 5120) { const int l = bid - 2048; src = Wqkv; dst = wqkvT; R = 1024; C = 3072; cx = l % 96; ry = l / 96; }
    else            { const int l = bid - 5120; src = Wproj; dst = wprojT; R = 1024; C = 1024; cx = l & 31; ry = l >> 5; }
    const int c0 = cx * 32, r0 = ry * 32;
    const int tx = t & 31, ty = t >> 5;
    for (int i = ty; i < 32; i += 8) tile[i][tx] = src[(size_t)(r0 + i) * C + c0 + tx];
    __syncthreads();
    for (int i = ty; i < 32; i += 8) dst[(size_t)(c0 + i) * R + r0 + tx] = f2b(tile[tx][i]);
  }
}

// ---------------- m97-structure bf16 GEMM (r9 measured best) + optional fused V-transpose ----------------
// WVT: for output cols >= 2048 (the V third of qkv), also write bf16 results transposed into
// vt[bh][d][n] (identical values incl. bias -> replaces the transpose_v kernel).
template <typename OutT, bool WVT>
__global__ __launch_bounds__(256) void gemm_bt_bias(
    const u16* __restrict__ A,     // [M][K] bf16
    const u16* __restrict__ BT,    // [N][K] bf16 (K contiguous)
    const float* __restrict__ bias,// [N] fp32
    OutT* __restrict__ C,          // [M][N]
    int M, int N, int K,
    u16* __restrict__ vt) {        // [B*H][64][2048] (WVT only)
  __shared__ alignas(16) u16 Als[128 * 32];
  __shared__ alignas(16) u16 Bls[128 * 32];
  const int m0 = blockIdx.x * 128, n0 = blockIdx.y * 128;
  const int t = threadIdx.x;
  const int w = t >> 6, lane = t & 63;
  const int wr = w >> 1, wc = w & 1;
  const int rlo = lane & 15, g = lane >> 4;

  f32x4 acc[4][4] = {};

  const int r0 = t >> 2;
  const int c0 = (t & 3) << 3;
  const u16* aSrc = A + (size_t)(m0 + r0) * K + c0;
  const u16* bSrc = BT + (size_t)(n0 + r0) * K + c0;

  for (int k0 = 0; k0 < K; k0 += 32) {
    __builtin_amdgcn_global_load_lds(AS1(aSrc + k0), AS3(&Als[t * 8]), 16, 0, 0);
    __builtin_amdgcn_global_load_lds(AS1(aSrc + (size_t)64 * K + k0), AS3(&Als[(t + 256) * 8]), 16, 0, 0);
    __builtin_amdgcn_global_load_lds(AS1(bSrc + k0), AS3(&Bls[t * 8]), 16, 0, 0);
    __builtin_amdgcn_global_load_lds(AS1(bSrc + (size_t)64 * K + k0), AS3(&Bls[(t + 256) * 8]), 16, 0, 0);
    __syncthreads();

    bf16x8 a[4], b[4];
    #pragma unroll
    for (int m = 0; m < 4; ++m)
      a[m] = *(const bf16x8*)&Als[(wr * 64 + m * 16 + rlo) * 32 + g * 8];
    #pragma unroll
    for (int n = 0; n < 4; ++n)
      b[n] = *(const bf16x8*)&Bls[(wc * 64 + n * 16 + rlo) * 32 + g * 8];
    #pragma unroll
    for (int m = 0; m < 4; ++m)
      #pragma unroll
      for (int n = 0; n < 4; ++n)
        acc[m][n] = __builtin_amdgcn_mfma_f32_16x16x32_bf16(a[m], b[n], acc[m][n], 0, 0, 0);
    __syncthreads();
  }

  #pragma unroll
  for (int n = 0; n < 4; ++n) {
    const int col = n0 + wc * 64 + n * 16 + rlo;
    const float bv = bias[col];
    #pragma unroll
    for (int m = 0; m < 4; ++m) {
      const int row = m0 + wr * 64 + m * 16 + g * 4;
      u16 tmp[4];
      #pragma unroll
      for (int i = 0; i < 4; ++i) {
        float r = acc[m][n][i] + bv;
        if constexpr (sizeof(OutT) == 2) {
          const u16 hv = f2b(r);
          C[(size_t)(row + i) * N + col] = (OutT)hv;
          if constexpr (WVT) tmp[i] = hv;
        } else {
          C[(size_t)(row + i) * N + col] = (OutT)r;
        }
      }
      if constexpr (WVT) {
        if (col >= 2048) {
          const int cv = col - 2048;
          const int h = cv >> 6, dd = cv & 63;
          const int b = row >> 11, nloc = row & 2047;  // tile never crosses a batch boundary
          uint2 pv;
          pv.x = (u32)tmp[0] | ((u32)tmp[1] << 16);
          pv.y = (u32)tmp[2] | ((u32)tmp[3] << 16);
          *(uint2*)&vt[(((size_t)(b * 16 + h)) * 64 + dd) * 2048 + nloc] = pv;
        }
      }
    }
  }
}

// ---------------- causal flash attention: (q-half x kv-subtile) wave split + DBUF staging (r15) ----------------
__global__ __launch_bounds__(256, 2) void attn_fwd(
    const u16* __restrict__ qkv,  // [B*N][3072] bf16; Q col 0, K col 1024
    const u16* __restrict__ VT,   // [B*H][64][2048] bf16
    u16* __restrict__ O) {        // [B*N][1024] bf16
  const int N = 2048, TD = 3072, D = 1024;
  const int bid = blockIdx.x;
  const int qp = bid >> 6, bh = bid & 63;
  const int b = bh >> 4, h = bh & 15;
  const int t = threadIdx.x, w = t >> 6, lane = t & 63;
  const int l31 = lane & 31, hi = lane >> 5;
  const int qh = w >> 1, st = w & 1;

  __shared__ alignas(16) u16 pool16[2][2][64 * 64];
  __shared__ float rsLds[2][32];
  float* poolf = (float*)&pool16[0][0][0];

  const int c1 = t, c2 = t + 256;
  const int r1 = c1 >> 3, sc1 = ((c1 & 7) ^ (r1 & 7)) * 8;
  const int r2 = c2 >> 3, sc2 = ((c2 & 7) ^ (r2 & 7)) * 8;
  const u16* kbase = qkv + (size_t)(b * N) * TD + D + h * 64;
  const u16* vbase = VT + (size_t)bh * 64 * N;

#define ASTAGE(buf, j0) do { \
    STG(kbase + (size_t)((j0) + r1) * TD + sc1, &pool16[buf][0][c1 * 8]); \
    STG(kbase + (size_t)((j0) + r2) * TD + sc2, &pool16[buf][0][c2 * 8]); \
    STG(vbase + (size_t)r1 * N + (j0) + sc1, &pool16[buf][1][c1 * 8]); \
    STG(vbase + (size_t)r2 * N + (j0) + sc2, &pool16[buf][1][c2 * 8]); } while (0)

  const float L2E = 1.44269504089f;
  const float NSH = -23.0830992f;  // -16*log2(e): p = exp2(s*L2E + NSH) = exp(s-16)

  for (int pass = 0; pass < 2; ++pass) {
    const int qt = pass ? (15 - qp) : qp;
    const int qbw = qt * 128 + qh * 64;

    bf16x8 qf[2][4];
    #pragma unroll
    for (int qs = 0; qs < 2; ++qs) {
      const u16* qp_ = qkv + ((size_t)(b * N) + qbw + qs * 32 + l31) * TD + h * 64 + hi * 8;
      #pragma unroll
      for (int c = 0; c < 4; ++c) {
        bf16x8 v = *(const bf16x8*)(qp_ + c * 16);
        #pragma unroll
        for (int j = 0; j < 8; ++j)
          v[j] = (short)f2b(b2f((u16)v[j]) * 0.125f);
        qf[qs][c] = v;
      }
    }

    f32x16 o_acc[2][2] = {};
    float psum[2] = {0.f, 0.f};
    const int jend = qt * 128 + 64;

    ASTAGE(0, 0);
    __syncthreads();

    int cur = 0;
    for (int j0 = 0; j0 <= jend; j0 += 64) {
      if (j0 + 64 <= jend) ASTAGE(cur ^ 1, j0 + 64);

      const int sb2 = j0 + st * 32;
      if (sb2 <= qbw + 63) {
        bf16x8 kf[4];
        {
          const int row = st * 32 + l31, sw = (row & 7) << 3;
          #pragma unroll
          for (int c = 0; c < 4; ++c)
            kf[c] = *(const bf16x8*)&pool16[cur][0][row * 64 + ((c * 16 + hi * 8) ^ sw)];
        }
        bf16x8 vf[2][2];
        #pragma unroll
        for (int dt = 0; dt < 2; ++dt) {
          const int row = dt * 32 + l31, sw = (row & 7) << 3;
          #pragma unroll
          for (int kc = 0; kc < 2; ++kc)
            vf[kc][dt] = *(const bf16x8*)&pool16[cur][1][row * 64 + ((st * 32 + kc * 16 + hi * 8) ^ sw)];
        }

        #pragma unroll
        for (int qs = 0; qs < 2; ++qs) {
          if (qs == 0 && sb2 > qbw + 31) continue;
          const int qr = qbw + qs * 32 + l31;
          f32x16 S = {};
          __builtin_amdgcn_s_setprio(1);
          #pragma unroll
          for (int c = 0; c < 4; ++c)
            S = __builtin_amdgcn_mfma_f32_32x32x16_bf16(kf[c], qf[qs][c], S, 0, 0, 0);
          __builtin_amdgcn_s_setprio(0);
          if (sb2 + 31 > qbw + qs * 32) {
            const int kvb = sb2 + 4 * hi;
            #pragma unroll
            for (int r = 0; r < 16; ++r)
              if (kvb + (r & 3) + 8 * (r >> 2) > qr) S[r] = -1e30f;
          }
          float p[16];
          #pragma unroll
          for (int r = 0; r < 16; ++r) p[r] = EXP2F(fmaf(S[r], L2E, NSH));
          float ps = 0.f;
          #pragma unroll
          for (int r = 0; r < 16; ++r) ps += p[r];
          psum[qs] += ps;
          u32 wq[8];
          #pragma unroll
          for (int i = 0; i < 8; ++i) wq[i] = cvt_pk_bf16(p[2 * i], p[2 * i + 1]);
          permswap(wq[0], wq[2]); permswap(wq[1], wq[3]);
          permswap(wq[4], wq[6]); permswap(wq[5], wq[7]);
          union { u32 u[4]; bf16x8 v; } pa0, pa1;
          pa0.u[0] = wq[0]; pa0.u[1] = wq[1]; pa0.u[2] = wq[2]; pa0.u[3] = wq[3];
          pa1.u[0] = wq[4]; pa1.u[1] = wq[5]; pa1.u[2] = wq[6]; pa1.u[3] = wq[7];
          __builtin_amdgcn_s_setprio(1);
          #pragma unroll
          for (int dt = 0; dt < 2; ++dt) {
            o_acc[qs][dt] = __builtin_amdgcn_mfma_f32_32x32x16_bf16(pa0.v, vf[0][dt], o_acc[qs][dt], 0, 0, 0);
            o_acc[qs][dt] = __builtin_amdgcn_mfma_f32_32x32x16_bf16(pa1.v, vf[1][dt], o_acc[qs][dt], 0, 0, 0);
          }
          __builtin_amdgcn_s_setprio(0);
        }
      }
      __syncthreads();
      cur ^= 1;
    }

    float rsown[2];
    #pragma unroll
    for (int qs = 0; qs < 2; ++qs)
      rsown[qs] = psum[qs] + __shfl_xor(psum[qs], 32, 64);

    #pragma unroll
    for (int qs = 0; qs < 2; ++qs) {
      if (st != qs) {
        #pragma unroll
        for (int dt = 0; dt < 2; ++dt)
          #pragma unroll
          for (int r = 0; r < 16; ++r)
            poolf[qh * 2048 + (dt * 16 + r) * 64 + lane] = o_acc[qs][dt][r];
        rsLds[qh][l31] = rsown[qs];
      }
      __syncthreads();
      if (st == qs) {
        const float inv = 1.0f / (rsown[qs] + rsLds[qh][l31]);
        #pragma unroll
        for (int r = 0; r < 16; ++r) {
          const int qrow = (r & 3) + 8 * (r >> 2) + 4 * hi;
          const float invq = __shfl(inv, qrow, 64);
          const int q = qbw + qs * 32 + qrow;
          #pragma unroll
          for (int dt = 0; dt < 2; ++dt) {
            const float val = o_acc[qs][dt][r] + poolf[qh * 2048 + (dt * 16 + r) * 64 + lane];
            O[((size_t)(b * N) + q) * D + h * 64 + dt * 32 + l31] = f2b(val * invq);
          }
        }
      }
      __syncthreads();
    }
  }
#undef ASTAGE
}

extern "C" void kernel_launch(void* const* d_in, const int* in_sizes, int n_in,
                              void* d_out, int out_size, void* d_ws, size_t ws_size,
                              hipStream_t stream) {
  const float* x     = (const float*)d_in[0];
  // d_in[1] = causal_mask (fp32): handled structurally, unused
  const float* Wqkv  = (const float*)d_in[2];
  const float* bqkv  = (const float*)d_in[3];
  const float* Wproj = (const float*)d_in[4];
  const float* bproj = (const float*)d_in[5];
  float* out = (float*)d_out;

  const int B = 4, N = 2048, D = 1024, H = 16;
  const int BN = B * N;    // 8192
  const int TD = 3 * D;    // 3072

  char* ws = (char*)d_ws;
  u16* qkv    = (u16*)(ws);                      // 50,331,648 B
  u16* vt     = (u16*)(ws + 50331648);           // 16,777,216 B
  u16* aout   = (u16*)(ws + 67108864);           // 16,777,216 B
  u16* wqkvT  = (u16*)(ws + 83886080);           //  6,291,456 B
  u16* wprojT = (u16*)(ws + 90177536);           //  2,097,152 B
  u16* xb     = (u16*)(ws + 92274688);           // 16,777,216 B

  // 1) fused prep: x->bf16 cast + both weight transposes
  prep<<<6144, 256, 0, stream>>>(x, xb, Wqkv, wqkvT, Wproj, wprojT);
  // 2) QKV projection (r9 structure) + fused V-transpose into vt
  gemm_bt_bias<u16, true><<<dim3(BN / 128, TD / 128), 256, 0, stream>>>(xb, wqkvT, bqkv, qkv, BN, TD, D, vt);
  // 3) causal flash attention, (q-half x kv-subtile) wave split + dbuf staging
  attn_fwd<<<512, 256, 0, stream>>>(qkv, vt, aout);
  // 4) output projection (fp32 out + bias)
  gemm_bt_bias<float, false><<<dim3(BN / 128, D / 128), 256, 0, stream>>>(aout, wprojT, bproj, out, BN, D, D, nullptr);
}